// Round 9
// baseline (582.022 us; speedup 1.0000x reference)
//
#include <hip/hip_runtime.h>

// GIN 2-layer forward, MI355X (gfx950). Round 9:
//  - gather: TRUE XCD affinity via s_getreg(HW_REG_XCC_ID); per-slice chunk
//    counters (chunk=256 nodes) + work stealing => slice stays in its XCD
//    pair's L2 regardless of dispatch mapping.
//  - gather MLP: 2 nodes/wave, unroll-8 per edge-group (32 lines in flight),
//    index loads batched before feature loads; NT agg stores.
//  - rest identical to round 8.

#define N_NODES 50000
#define N_EDGES 800000
#define DIM 128
#define BN_EPS 1e-5f
#define NB 196                  // ceil(N_NODES/256) scan blocks
#define GEMM_GRID 782           // ceil(N_NODES/64)
#define NBUCK 256
#define NPB 196                 // nodes per bucket
#define BCAP 4096               // max edges per bucket
#define BINA_BLOCKS 128
#define EPB (N_EDGES / BINA_BLOCKS)
#define CHUNK_NODES 256
#define NCHUNK 196              // ceil(50000/256)

using bfrag8 = __attribute__((ext_vector_type(8))) short;
using accf4  = __attribute__((ext_vector_type(4))) float;

__device__ __forceinline__ float bf2f(unsigned short u) {
  union { unsigned u32; float f; } c;
  c.u32 = ((unsigned)u) << 16;
  return c.f;
}
__device__ __forceinline__ unsigned short f2bf(float f) {
  union { float f; unsigned u32; } c;
  c.f = f;
  unsigned u = c.u32;
  return (unsigned short)((u + 0x7fffu + ((u >> 16) & 1u)) >> 16);  // RNE
}

// ---- dtype detector ----
__global__ void detect_kernel(const unsigned short* __restrict__ xs,
                              int* __restrict__ flag) {
  __shared__ int oks[64];
  int t = threadIdx.x;
  unsigned short u = xs[t * 2];
  int e = (u >> 7) & 0xFF;
  oks[t] = ((e >= 96 && e <= 134) || ((u & 0x7FFFu) == 0)) ? 1 : 0;
  __syncthreads();
  if (t == 0) {
    int c = 0;
    for (int i = 0; i < 64; ++i) c += oks[i];
    *flag = (c >= 56) ? 1 : 0;  // 1 = bf16, 0 = fp32
  }
}

// ---- prep: pack weights into MFMA B-frag layout + convert vectors ----
struct PPtrs { const void* w[4]; const void* v[10]; };

__global__ __launch_bounds__(256) void prep_kernel(
    PPtrs pp, unsigned short* __restrict__ PW, float* __restrict__ PV,
    const int* __restrict__ flagp) {
  int bf = *flagp;
  if (blockIdx.x < 4) {
    int mat = blockIdx.x;
    const void* src = pp.w[mat];
    unsigned short* dst = PW + (size_t)mat * 16384;
    for (int f = threadIdx.x; f < 2048; f += 256) {
      int kt = f >> 9, nt = (f >> 6) & 7, lane = f & 63;
      int kbase = kt * 32 + (lane >> 4) * 8;
      int n = nt * 16 + (lane & 15);
      unsigned short tmp[8];
      for (int j = 0; j < 8; ++j) {
        int idx = (kbase + j) * DIM + n;
        if (bf) tmp[j] = ((const unsigned short*)src)[idx];
        else    tmp[j] = f2bf(((const float*)src)[idx]);
      }
      for (int j = 0; j < 8; ++j) dst[f * 8 + j] = tmp[j];
    }
  } else {
    for (int j = threadIdx.x; j < 10 * DIM; j += 256) {
      int vec = j >> 7, idx = j & 127;
      float v;
      if (bf) v = bf2f(((const unsigned short*)pp.v[vec])[idx]);
      else    v = ((const float*)pp.v[vec])[idx];
      PV[j] = v;
    }
  }
}

// ================= CSR build =================
__global__ __launch_bounds__(256) void binA_kernel(
    const int* __restrict__ row, const int* __restrict__ col,
    int* __restrict__ deg, int* __restrict__ bcnt, uint2* __restrict__ ebuf) {
  __shared__ int hist[NBUCK];
  __shared__ int base[NBUCK];
  int t = threadIdx.x;
  int e0 = blockIdx.x * EPB;
  hist[t] = 0;
  __syncthreads();
  for (int i = t; i < EPB; i += 256) {
    int r = row[e0 + i];
    atomicAdd(&deg[r], 1);
    atomicAdd(&hist[r / NPB], 1);
  }
  __syncthreads();
  base[t] = atomicAdd(&bcnt[t], hist[t]);
  hist[t] = 0;
  __syncthreads();
  for (int i = t; i < EPB; i += 256) {
    int r = row[e0 + i];
    int c = col[e0 + i];
    int b = r / NPB;
    int rank = atomicAdd(&hist[b], 1);
    ebuf[(size_t)b * BCAP + base[b] + rank] = make_uint2((unsigned)r, (unsigned)c);
  }
}

__global__ __launch_bounds__(256) void bsum_kernel(
    const int* __restrict__ deg, int* __restrict__ bsum) {
  __shared__ int s[256];
  int i = blockIdx.x * 256 + threadIdx.x;
  s[threadIdx.x] = (i < N_NODES) ? deg[i] : 0;
  __syncthreads();
  for (int d = 128; d > 0; d >>= 1) {
    if (threadIdx.x < d) s[threadIdx.x] += s[threadIdx.x + d];
    __syncthreads();
  }
  if (threadIdx.x == 0) bsum[blockIdx.x] = s[0];
}

__global__ __launch_bounds__(256) void bscan_kernel(
    const int* __restrict__ bsum, int* __restrict__ bscan) {
  __shared__ int s[256];
  int t = threadIdx.x;
  int v = (t < NB) ? bsum[t] : 0;
  s[t] = v;
  __syncthreads();
  for (int d = 1; d < 256; d <<= 1) {
    int tv = (t >= d) ? s[t - d] : 0;
    __syncthreads();
    s[t] += tv;
    __syncthreads();
  }
  if (t < NB) bscan[t] = s[t] - v;  // exclusive
}

__global__ __launch_bounds__(256) void offs_kernel(
    const int* __restrict__ deg, const int* __restrict__ bscan,
    int* __restrict__ offs) {
  __shared__ int s[256];
  int t = threadIdx.x;
  int i = blockIdx.x * 256 + t;
  int v = (i < N_NODES) ? deg[i] : 0;
  s[t] = v;
  __syncthreads();
  for (int d = 1; d < 256; d <<= 1) {
    int tv = (t >= d) ? s[t - d] : 0;
    __syncthreads();
    s[t] += tv;
    __syncthreads();
  }
  if (i < N_NODES) {
    int excl = bscan[blockIdx.x] + s[t] - v;
    offs[i] = excl;
    if (i == N_NODES - 1) offs[N_NODES] = excl + v;
  }
}

__global__ __launch_bounds__(256) void binB_kernel(
    const int* __restrict__ offs, const int* __restrict__ bcnt,
    const uint2* __restrict__ ebuf, int* __restrict__ csr_col) {
  __shared__ int cur[NPB];
  __shared__ int seg[BCAP];
  int b = blockIdx.x;
  int nb = b * NPB;
  int nend = nb + NPB;
  if (nend > N_NODES) nend = N_NODES;
  int nn = nend - nb;
  int segbase = offs[nb];
  int seglen = offs[nend] - segbase;
  for (int i = threadIdx.x; i < nn; i += 256) cur[i] = offs[nb + i] - segbase;
  __syncthreads();
  int cnt = bcnt[b];
  const uint2* eb = ebuf + (size_t)b * BCAP;
  for (int i = threadIdx.x; i < cnt; i += 256) {
    uint2 e = eb[i];
    int slot = atomicAdd(&cur[e.x - (unsigned)nb], 1);
    seg[slot] = (int)e.y;
  }
  __syncthreads();
  for (int i = threadIdx.x; i < seglen; i += 256)
    csr_col[segbase + i] = seg[i];
}

// ================= XCC-affine work-stealing gather =================
// Block reads its real XCD id; slice = xcc>>1 (4 slices x 2 XCDs).
// Per-slice chunk counters (chunk = 256 nodes); steal other slices when
// own slice is drained (correctness independent of dispatch mapping).
// Wave handles 2 nodes (half = lane>>5); per node: e2 = edge-group (stride 2),
// unroll-8 => 16 feature lines in flight per node, 32 per wave.
__global__ __launch_bounds__(256) void gather_kernel(
    const void* __restrict__ src, const int* __restrict__ offs,
    const int* __restrict__ csr_col, const float* __restrict__ ss,
    unsigned short* __restrict__ agg, const int* __restrict__ flagp,
    int* __restrict__ ctr, int mode) {
  __shared__ int chunk_s;
  int xcc;
  asm volatile("s_getreg_b32 %0, hwreg(HW_REG_XCC_ID)" : "=s"(xcc));
  int myslice = (xcc & 7) >> 1;
  const int tid = threadIdx.x;
  const int wv = tid >> 6;
  const int lane = tid & 63;
  const int half = lane >> 5;
  const int e2 = (lane >> 4) & 1;
  const int c2 = lane & 15;
  const int bf = *flagp;

  for (int s4 = 0; s4 < 4; ++s4) {
    int sl = (myslice + s4) & 3;
    int ch = sl * 32 + c2 * 2;
    float sc0 = 0.f, sc1 = 0.f, sh0 = 0.f, sh1 = 0.f;
    if (mode == 1) {
      sc0 = ss[ch]; sc1 = ss[ch + 1];
      sh0 = ss[DIM + ch]; sh1 = ss[DIM + ch + 1];
    }
    while (true) {
      if (tid == 0) {
        int c = __atomic_load_n(ctr + sl, __ATOMIC_RELAXED);
        if (c < NCHUNK) c = atomicAdd(ctr + sl, 1);
        chunk_s = c;
      }
      __syncthreads();
      int chunk = chunk_s;
      __syncthreads();
      if (chunk >= NCHUNK) break;
      int nbase = chunk * CHUNK_NODES + wv * 2 + half;
      for (int it = 0; it < CHUNK_NODES / 8; ++it) {
        int node = nbase + it * 8;
        if (node >= N_NODES) break;
        int start = offs[node], end = offs[node + 1];
        float a0 = 0.f, a1 = 0.f;
        if (mode == 1 || bf) {
          const unsigned short* h = (const unsigned short*)src;
          int j = start + e2;
          for (; j + 14 < end; j += 16) {
            int ix[8];
#pragma unroll
            for (int k = 0; k < 8; ++k) ix[k] = csr_col[j + 2 * k];
            unsigned u[8];
#pragma unroll
            for (int k = 0; k < 8; ++k)
              u[k] = *(const unsigned*)(h + (size_t)ix[k] * DIM + ch);
            if (mode == 1) {
#pragma unroll
              for (int k = 0; k < 8; ++k) {
                a0 += fmaxf(bf2f((unsigned short)u[k]) * sc0 + sh0, 0.f);
                a1 += fmaxf(bf2f((unsigned short)(u[k] >> 16)) * sc1 + sh1, 0.f);
              }
            } else {
#pragma unroll
              for (int k = 0; k < 8; ++k) {
                a0 += bf2f((unsigned short)u[k]);
                a1 += bf2f((unsigned short)(u[k] >> 16));
              }
            }
          }
          for (; j < end; j += 2) {
            unsigned u = *(const unsigned*)(h + (size_t)csr_col[j] * DIM + ch);
            if (mode == 1) {
              a0 += fmaxf(bf2f((unsigned short)u) * sc0 + sh0, 0.f);
              a1 += fmaxf(bf2f((unsigned short)(u >> 16)) * sc1 + sh1, 0.f);
            } else {
              a0 += bf2f((unsigned short)u);
              a1 += bf2f((unsigned short)(u >> 16));
            }
          }
        } else {
          const float* x = (const float*)src;
          int j = start + e2;
          for (; j + 14 < end; j += 16) {
            int ix[8];
#pragma unroll
            for (int k = 0; k < 8; ++k) ix[k] = csr_col[j + 2 * k];
#pragma unroll
            for (int k = 0; k < 8; ++k) {
              float2 v = *(const float2*)(x + (size_t)ix[k] * DIM + ch);
              a0 += v.x; a1 += v.y;
            }
          }
          for (; j < end; j += 2) {
            float2 v = *(const float2*)(x + (size_t)csr_col[j] * DIM + ch);
            a0 += v.x; a1 += v.y;
          }
        }
        a0 += __shfl_down(a0, 16);
        a1 += __shfl_down(a1, 16);
        if (e2 == 0) {
          unsigned o = (unsigned)f2bf(a0) | ((unsigned)f2bf(a1) << 16);
          __builtin_nontemporal_store(
              o, (unsigned*)(agg + (size_t)node * DIM + ch));
        }
      }
    }
  }
}

// ---- BN finalize: one block per channel ----
__global__ __launch_bounds__(256) void bn_fin_kernel(
    const float* __restrict__ ps, const float* __restrict__ g,
    const float* __restrict__ be, float* __restrict__ ss) {
  __shared__ float s2[256], q2[256];
  int c = blockIdx.x;
  int t = threadIdx.x;
  float s = 0.f, q = 0.f;
  for (int b = t; b < GEMM_GRID; b += 256) {
    s += ps[b * 256 + c];
    q += ps[b * 256 + 128 + c];
  }
  s2[t] = s; q2[t] = q;
  __syncthreads();
  for (int d = 128; d > 0; d >>= 1) {
    if (t < d) { s2[t] += s2[t + d]; q2[t] += q2[t + d]; }
    __syncthreads();
  }
  if (t == 0) {
    const float invN = 1.0f / (float)N_NODES;
    float m = s2[0] * invN;
    float v = q2[0] * invN - m * m;
    float scale = g[c] * rsqrtf(v + BN_EPS);
    ss[c] = scale;
    ss[DIM + c] = be[c] - m * scale;
  }
}

// ================= MFMA GEMM =================
__global__ __launch_bounds__(256) void gemm_kernel(
    const void* __restrict__ Ap, const unsigned short* __restrict__ agg,
    const unsigned short* __restrict__ PWm, const float* __restrict__ bias,
    const float* __restrict__ ss, void* __restrict__ Cp,
    float* __restrict__ ps, const int* __restrict__ flagp,
    int a_ext, int add_agg, int transform, int out_ext, int do_stats) {
  __shared__ unsigned short As[64 * 136];
  __shared__ float red_s[256];
  __shared__ float red_q[256];
  const int tid = threadIdx.x;
  const int row0 = blockIdx.x * 64;
  const int bf = *flagp;

  for (int i = 0; i < 8; ++i) {
    int G = tid + i * 256;
    int lrow = G >> 5;
    int ch = (G & 31) * 4;
    int grow = row0 + lrow;
    float4 v = make_float4(0.f, 0.f, 0.f, 0.f);
    if (grow < N_NODES) {
      if (a_ext && !bf) {
        v = *(const float4*)((const float*)Ap + (size_t)grow * DIM + ch);
      } else {
        ushort4 u = *(const ushort4*)((const unsigned short*)Ap +
                                      (size_t)grow * DIM + ch);
        v = make_float4(bf2f(u.x), bf2f(u.y), bf2f(u.z), bf2f(u.w));
      }
      if (transform) {
        float4 sc = *(const float4*)(ss + ch);
        float4 sh = *(const float4*)(ss + DIM + ch);
        v.x = fmaxf(v.x * sc.x + sh.x, 0.f);
        v.y = fmaxf(v.y * sc.y + sh.y, 0.f);
        v.z = fmaxf(v.z * sc.z + sh.z, 0.f);
        v.w = fmaxf(v.w * sc.w + sh.w, 0.f);
      }
      if (add_agg) {
        ushort4 au = *(const ushort4*)(agg + (size_t)grow * DIM + ch);
        v.x += bf2f(au.x); v.y += bf2f(au.y);
        v.z += bf2f(au.z); v.w += bf2f(au.w);
      }
    }
    ushort4 o;
    o.x = f2bf(v.x); o.y = f2bf(v.y); o.z = f2bf(v.z); o.w = f2bf(v.w);
    *(ushort4*)&As[lrow * 136 + ch] = o;
  }
  __syncthreads();

  const int wv = tid >> 6, lane = tid & 63;
  const int quad = lane >> 4, lo = lane & 15;
  accf4 acc[8];
#pragma unroll
  for (int nt = 0; nt < 8; ++nt) {
    acc[nt][0] = 0.f; acc[nt][1] = 0.f; acc[nt][2] = 0.f; acc[nt][3] = 0.f;
  }
#pragma unroll
  for (int kt = 0; kt < 4; ++kt) {
    bfrag8 a = *(const bfrag8*)&As[(wv * 16 + lo) * 136 + kt * 32 + quad * 8];
    const unsigned short* pw = PWm + kt * 4096 + lane * 8;
#pragma unroll
    for (int nt = 0; nt < 8; ++nt) {
      bfrag8 b = *(const bfrag8*)(pw + nt * 512);
      acc[nt] = __builtin_amdgcn_mfma_f32_16x16x32_bf16(a, b, acc[nt], 0, 0, 0);
    }
  }
  __syncthreads();

  if (out_ext && !bf) {
    float* Co = (float*)Cp;
#pragma unroll
    for (int nt = 0; nt < 8; ++nt) {
      float b = bias[nt * 16 + lo];
#pragma unroll
      for (int reg = 0; reg < 4; ++reg) {
        int grow = row0 + wv * 16 + quad * 4 + reg;
        if (grow < N_NODES)
          Co[(size_t)grow * DIM + nt * 16 + lo] = acc[nt][reg] + b;
      }
    }
  } else {
#pragma unroll
    for (int nt = 0; nt < 8; ++nt) {
      float b = bias[nt * 16 + lo];
#pragma unroll
      for (int reg = 0; reg < 4; ++reg) {
        As[(wv * 16 + quad * 4 + reg) * 136 + nt * 16 + lo] =
            f2bf(acc[nt][reg] + b);
      }
    }
    __syncthreads();
    unsigned short* Co = (unsigned short*)Cp;
    for (int i = 0; i < 8; ++i) {
      int G = tid + i * 256;
      int lrow = G >> 5, ch = (G & 31) * 4;
      int grow = row0 + lrow;
      if (grow < N_NODES)
        *(ushort4*)(Co + (size_t)grow * DIM + ch) =
            *(const ushort4*)&As[lrow * 136 + ch];
    }
    if (do_stats) {
      int c = tid & 127, rh = tid >> 7;
      int rmax = N_NODES - row0;
      if (rmax > 64) rmax = 64;
      int rend = rh * 32 + 32;
      if (rend > rmax) rend = rmax;
      float s = 0.f, q = 0.f;
      for (int r = rh * 32; r < rend; ++r) {
        float v = bf2f(As[r * 136 + c]);
        s += v; q += v * v;
      }
      red_s[tid] = s; red_q[tid] = q;
      __syncthreads();
      if (tid < 128) {
        ps[blockIdx.x * 256 + tid] = red_s[tid] + red_s[tid + 128];
        ps[blockIdx.x * 256 + 128 + tid] = red_q[tid] + red_q[tid + 128];
      }
    }
  }
}

extern "C" void kernel_launch(void* const* d_in, const int* in_sizes, int n_in,
                              void* d_out, int out_size, void* d_ws, size_t ws_size,
                              hipStream_t stream) {
  const void* x  = d_in[0];
  const int* row = (const int*)d_in[1];
  const int* col = (const int*)d_in[2];

  const size_t ND = (size_t)N_NODES * DIM;
  unsigned short* agg = (unsigned short*)d_ws;        // ND bf16
  unsigned short* hA  = agg + ND;                     // ND bf16
  unsigned short* hB  = hA + ND;                      // ND bf16
  unsigned short* PW  = hB + ND;                      // 4*16384 bf16
  float* PV    = (float*)(PW + 4 * 16384);            // 10*128 fp32
  float* ps    = PV + 10 * DIM;                       // GEMM_GRID*256 fp32
  float* ss    = ps + GEMM_GRID * 256;                // 3*256 fp32
  int*   flag  = (int*)(ss + 3 * 256);                // 1 (+pad)
  int*   wctr  = flag + 4;                            // 8 (2x4 slice counters)
  int*   deg   = wctr + 8;                            // N
  int*   bcnt  = deg + N_NODES;                       // NBUCK
  int*   offs  = bcnt + NBUCK;                        // N+1
  int*   bsum  = offs + N_NODES + 1;                  // 256
  int*   bscan = bsum + 256;                          // 256
  int*   csr_col = bscan + 256;                       // E
  uint2* ebuf  = (uint2*)((((size_t)(csr_col + N_EDGES)) + 15) & ~(size_t)15);

  float* c0_b1f = PV + 0 * DIM; float* c0_gf  = PV + 1 * DIM;
  float* c0_bef = PV + 2 * DIM; float* c0_b2f = PV + 3 * DIM;
  float* bn0_gf = PV + 4 * DIM; float* bn0_bef= PV + 5 * DIM;
  float* c1_b1f = PV + 6 * DIM; float* c1_gf  = PV + 7 * DIM;
  float* c1_bef = PV + 8 * DIM; float* c1_b2f = PV + 9 * DIM;

  detect_kernel<<<1, 64, 0, stream>>>((const unsigned short*)x, flag);

  PPtrs pp;
  pp.w[0] = d_in[3];  pp.w[1] = d_in[7];  pp.w[2] = d_in[11]; pp.w[3] = d_in[15];
  pp.v[0] = d_in[4];  pp.v[1] = d_in[5];  pp.v[2] = d_in[6];  pp.v[3] = d_in[8];
  pp.v[4] = d_in[9];  pp.v[5] = d_in[10]; pp.v[6] = d_in[12]; pp.v[7] = d_in[13];
  pp.v[8] = d_in[14]; pp.v[9] = d_in[16];
  prep_kernel<<<5, 256, 0, stream>>>(pp, PW, PV, flag);

  // zero wctr(8) + deg(N) + bcnt(NBUCK) in one shot
  hipMemsetAsync(wctr, 0, (8 + N_NODES + NBUCK) * sizeof(int), stream);

  // ---- CSR build ----
  binA_kernel<<<BINA_BLOCKS, 256, 0, stream>>>(row, col, deg, bcnt, ebuf);
  bsum_kernel<<<NB, 256, 0, stream>>>(deg, bsum);
  bscan_kernel<<<1, 256, 0, stream>>>(bsum, bscan);
  offs_kernel<<<NB, 256, 0, stream>>>(deg, bscan, offs);
  binB_kernel<<<NBUCK, 256, 0, stream>>>(offs, bcnt, ebuf, csr_col);

  // ---- conv0 ----
  gather_kernel<<<1024, 256, 0, stream>>>(x, offs, csr_col, nullptr,
                                          agg, flag, wctr, 0);
  gemm_kernel<<<GEMM_GRID, 256, 0, stream>>>(
      x, agg, PW + 0 * 16384, c0_b1f, nullptr, hA, ps, flag,
      1, 1, 0, 0, 1);
  bn_fin_kernel<<<128, 256, 0, stream>>>(ps, c0_gf, c0_bef, ss + 0);
  gemm_kernel<<<GEMM_GRID, 256, 0, stream>>>(
      hA, nullptr, PW + 1 * 16384, c0_b2f, ss + 0, hB, ps, flag,
      0, 0, 1, 0, 1);
  bn_fin_kernel<<<128, 256, 0, stream>>>(ps, bn0_gf, bn0_bef, ss + 256);

  // ---- conv1 ----
  gather_kernel<<<1024, 256, 0, stream>>>(hB, offs, csr_col, ss + 256,
                                          agg, flag, wctr + 4, 1);
  gemm_kernel<<<GEMM_GRID, 256, 0, stream>>>(
      hB, agg, PW + 2 * 16384, c1_b1f, ss + 256, hA, ps, flag,
      0, 1, 1, 0, 1);
  bn_fin_kernel<<<128, 256, 0, stream>>>(ps, c1_gf, c1_bef, ss + 512);
  gemm_kernel<<<GEMM_GRID, 256, 0, stream>>>(
      hA, nullptr, PW + 3 * 16384, c1_b2f, ss + 512, d_out, nullptr, flag,
      0, 0, 1, 1, 0);
}

// Round 10
// 391.301 us; speedup vs baseline: 1.4874x; 1.4874x over previous
//
#include <hip/hip_runtime.h>

// GIN 2-layer forward, MI355X (gfx950). Round 10:
//  - revert gather to round-8 sliced form for layer 1 (proven 88us baseline)
//  - layer 0 uses a NEW full-row gather (1 wave-instr = whole 256B row,
//    4x fewer memory instructions, unroll-8 = 32 lines in flight) as an
//    in-run A/B test of the "transaction-bound not fetch-bound" theory.
//  - rest identical to round 8.

#define N_NODES 50000
#define N_EDGES 800000
#define DIM 128
#define BN_EPS 1e-5f
#define NB 196                  // ceil(N_NODES/256) scan blocks
#define GEMM_GRID 782           // ceil(N_NODES/64)
#define NBUCK 256
#define NPB 196                 // nodes per bucket
#define BCAP 4096               // max edges per bucket
#define BINA_BLOCKS 128
#define EPB (N_EDGES / BINA_BLOCKS)

using bfrag8 = __attribute__((ext_vector_type(8))) short;
using accf4  = __attribute__((ext_vector_type(4))) float;

__device__ __forceinline__ float bf2f(unsigned short u) {
  union { unsigned u32; float f; } c;
  c.u32 = ((unsigned)u) << 16;
  return c.f;
}
__device__ __forceinline__ unsigned short f2bf(float f) {
  union { float f; unsigned u32; } c;
  c.f = f;
  unsigned u = c.u32;
  return (unsigned short)((u + 0x7fffu + ((u >> 16) & 1u)) >> 16);  // RNE
}

// ---- dtype detector ----
__global__ void detect_kernel(const unsigned short* __restrict__ xs,
                              int* __restrict__ flag) {
  __shared__ int oks[64];
  int t = threadIdx.x;
  unsigned short u = xs[t * 2];
  int e = (u >> 7) & 0xFF;
  oks[t] = ((e >= 96 && e <= 134) || ((u & 0x7FFFu) == 0)) ? 1 : 0;
  __syncthreads();
  if (t == 0) {
    int c = 0;
    for (int i = 0; i < 64; ++i) c += oks[i];
    *flag = (c >= 56) ? 1 : 0;  // 1 = bf16, 0 = fp32
  }
}

// ---- prep: pack weights into MFMA B-frag layout + convert vectors ----
struct PPtrs { const void* w[4]; const void* v[10]; };

__global__ __launch_bounds__(256) void prep_kernel(
    PPtrs pp, unsigned short* __restrict__ PW, float* __restrict__ PV,
    const int* __restrict__ flagp) {
  int bf = *flagp;
  if (blockIdx.x < 4) {
    int mat = blockIdx.x;
    const void* src = pp.w[mat];
    unsigned short* dst = PW + (size_t)mat * 16384;
    for (int f = threadIdx.x; f < 2048; f += 256) {
      int kt = f >> 9, nt = (f >> 6) & 7, lane = f & 63;
      int kbase = kt * 32 + (lane >> 4) * 8;
      int n = nt * 16 + (lane & 15);
      unsigned short tmp[8];
      for (int j = 0; j < 8; ++j) {
        int idx = (kbase + j) * DIM + n;
        if (bf) tmp[j] = ((const unsigned short*)src)[idx];
        else    tmp[j] = f2bf(((const float*)src)[idx]);
      }
      for (int j = 0; j < 8; ++j) dst[f * 8 + j] = tmp[j];
    }
  } else {
    for (int j = threadIdx.x; j < 10 * DIM; j += 256) {
      int vec = j >> 7, idx = j & 127;
      float v;
      if (bf) v = bf2f(((const unsigned short*)pp.v[vec])[idx]);
      else    v = ((const float*)pp.v[vec])[idx];
      PV[j] = v;
    }
  }
}

// ================= CSR build =================
__global__ __launch_bounds__(256) void binA_kernel(
    const int* __restrict__ row, const int* __restrict__ col,
    int* __restrict__ deg, int* __restrict__ bcnt, uint2* __restrict__ ebuf) {
  __shared__ int hist[NBUCK];
  __shared__ int base[NBUCK];
  int t = threadIdx.x;
  int e0 = blockIdx.x * EPB;
  hist[t] = 0;
  __syncthreads();
  for (int i = t; i < EPB; i += 256) {
    int r = row[e0 + i];
    atomicAdd(&deg[r], 1);
    atomicAdd(&hist[r / NPB], 1);
  }
  __syncthreads();
  base[t] = atomicAdd(&bcnt[t], hist[t]);
  hist[t] = 0;
  __syncthreads();
  for (int i = t; i < EPB; i += 256) {
    int r = row[e0 + i];
    int c = col[e0 + i];
    int b = r / NPB;
    int rank = atomicAdd(&hist[b], 1);
    ebuf[(size_t)b * BCAP + base[b] + rank] = make_uint2((unsigned)r, (unsigned)c);
  }
}

__global__ __launch_bounds__(256) void bsum_kernel(
    const int* __restrict__ deg, int* __restrict__ bsum) {
  __shared__ int s[256];
  int i = blockIdx.x * 256 + threadIdx.x;
  s[threadIdx.x] = (i < N_NODES) ? deg[i] : 0;
  __syncthreads();
  for (int d = 128; d > 0; d >>= 1) {
    if (threadIdx.x < d) s[threadIdx.x] += s[threadIdx.x + d];
    __syncthreads();
  }
  if (threadIdx.x == 0) bsum[blockIdx.x] = s[0];
}

__global__ __launch_bounds__(256) void bscan_kernel(
    const int* __restrict__ bsum, int* __restrict__ bscan) {
  __shared__ int s[256];
  int t = threadIdx.x;
  int v = (t < NB) ? bsum[t] : 0;
  s[t] = v;
  __syncthreads();
  for (int d = 1; d < 256; d <<= 1) {
    int tv = (t >= d) ? s[t - d] : 0;
    __syncthreads();
    s[t] += tv;
    __syncthreads();
  }
  if (t < NB) bscan[t] = s[t] - v;  // exclusive
}

__global__ __launch_bounds__(256) void offs_kernel(
    const int* __restrict__ deg, const int* __restrict__ bscan,
    int* __restrict__ offs) {
  __shared__ int s[256];
  int t = threadIdx.x;
  int i = blockIdx.x * 256 + t;
  int v = (i < N_NODES) ? deg[i] : 0;
  s[t] = v;
  __syncthreads();
  for (int d = 1; d < 256; d <<= 1) {
    int tv = (t >= d) ? s[t - d] : 0;
    __syncthreads();
    s[t] += tv;
    __syncthreads();
  }
  if (i < N_NODES) {
    int excl = bscan[blockIdx.x] + s[t] - v;
    offs[i] = excl;
    if (i == N_NODES - 1) offs[N_NODES] = excl + v;
  }
}

__global__ __launch_bounds__(256) void binB_kernel(
    const int* __restrict__ offs, const int* __restrict__ bcnt,
    const uint2* __restrict__ ebuf, int* __restrict__ csr_col) {
  __shared__ int cur[NPB];
  __shared__ int seg[BCAP];
  int b = blockIdx.x;
  int nb = b * NPB;
  int nend = nb + NPB;
  if (nend > N_NODES) nend = N_NODES;
  int nn = nend - nb;
  int segbase = offs[nb];
  int seglen = offs[nend] - segbase;
  for (int i = threadIdx.x; i < nn; i += 256) cur[i] = offs[nb + i] - segbase;
  __syncthreads();
  int cnt = bcnt[b];
  const uint2* eb = ebuf + (size_t)b * BCAP;
  for (int i = threadIdx.x; i < cnt; i += 256) {
    uint2 e = eb[i];
    int slot = atomicAdd(&cur[e.x - (unsigned)nb], 1);
    seg[slot] = (int)e.y;
  }
  __syncthreads();
  for (int i = threadIdx.x; i < seglen; i += 256)
    csr_col[segbase + i] = seg[i];
}

// ================= NEW: full-row gather (A/B candidate) =================
// Wave = 1 node; lane owns 2 channels (4B bf16 / 8B fp32) => one wave
// instruction reads the entire feature row. Unroll-8 => 8 rows (32 lines)
// in flight. mode 0: plain sum; mode 1: relu(v*sc+sh) per neighbor.
__global__ __launch_bounds__(256) void gather_row_kernel(
    const void* __restrict__ src, const int* __restrict__ offs,
    const int* __restrict__ csr_col, const float* __restrict__ ss,
    unsigned short* __restrict__ agg, const int* __restrict__ flagp,
    int mode) {
  int node = blockIdx.x * 4 + (threadIdx.x >> 6);
  if (node >= N_NODES) return;
  int lane = threadIdx.x & 63;
  int ch = lane * 2;
  int start = offs[node], end = offs[node + 1];
  float a0 = 0.f, a1 = 0.f;
  int bf = *flagp;
  float sc0 = 0.f, sc1 = 0.f, sh0 = 0.f, sh1 = 0.f;
  if (mode == 1) {
    sc0 = ss[ch]; sc1 = ss[ch + 1];
    sh0 = ss[DIM + ch]; sh1 = ss[DIM + ch + 1];
  }

  if (mode == 1 || bf) {
    const unsigned short* h = (const unsigned short*)src;
    int j = start;
    for (; j + 7 < end; j += 8) {
      int ix[8];
#pragma unroll
      for (int k = 0; k < 8; ++k) ix[k] = csr_col[j + k];
      unsigned u[8];
#pragma unroll
      for (int k = 0; k < 8; ++k)
        u[k] = *(const unsigned*)(h + (size_t)ix[k] * DIM + ch);
      if (mode == 1) {
#pragma unroll
        for (int k = 0; k < 8; ++k) {
          a0 += fmaxf(bf2f((unsigned short)u[k]) * sc0 + sh0, 0.f);
          a1 += fmaxf(bf2f((unsigned short)(u[k] >> 16)) * sc1 + sh1, 0.f);
        }
      } else {
#pragma unroll
        for (int k = 0; k < 8; ++k) {
          a0 += bf2f((unsigned short)u[k]);
          a1 += bf2f((unsigned short)(u[k] >> 16));
        }
      }
    }
    if (j + 3 < end) {
      int ix[4];
#pragma unroll
      for (int k = 0; k < 4; ++k) ix[k] = csr_col[j + k];
      unsigned u[4];
#pragma unroll
      for (int k = 0; k < 4; ++k)
        u[k] = *(const unsigned*)(h + (size_t)ix[k] * DIM + ch);
#pragma unroll
      for (int k = 0; k < 4; ++k) {
        if (mode == 1) {
          a0 += fmaxf(bf2f((unsigned short)u[k]) * sc0 + sh0, 0.f);
          a1 += fmaxf(bf2f((unsigned short)(u[k] >> 16)) * sc1 + sh1, 0.f);
        } else {
          a0 += bf2f((unsigned short)u[k]);
          a1 += bf2f((unsigned short)(u[k] >> 16));
        }
      }
      j += 4;
    }
    for (; j < end; ++j) {
      unsigned u = *(const unsigned*)(h + (size_t)csr_col[j] * DIM + ch);
      if (mode == 1) {
        a0 += fmaxf(bf2f((unsigned short)u) * sc0 + sh0, 0.f);
        a1 += fmaxf(bf2f((unsigned short)(u >> 16)) * sc1 + sh1, 0.f);
      } else {
        a0 += bf2f((unsigned short)u);
        a1 += bf2f((unsigned short)(u >> 16));
      }
    }
  } else {
    const float* x = (const float*)src;
    int j = start;
    for (; j + 7 < end; j += 8) {
      int ix[8];
#pragma unroll
      for (int k = 0; k < 8; ++k) ix[k] = csr_col[j + k];
#pragma unroll
      for (int k = 0; k < 8; ++k) {
        float2 v = *(const float2*)(x + (size_t)ix[k] * DIM + ch);
        a0 += v.x; a1 += v.y;
      }
    }
    for (; j < end; ++j) {
      float2 v = *(const float2*)(x + (size_t)csr_col[j] * DIM + ch);
      a0 += v.x; a1 += v.y;
    }
  }
  unsigned o = (unsigned)f2bf(a0) | ((unsigned)f2bf(a1) << 16);
  *(unsigned*)(agg + (size_t)node * DIM + ch) = o;
}

// ================= round-8 sliced gather (proven baseline) =================
__global__ __launch_bounds__(256) void gather_kernel(
    const void* __restrict__ src, const int* __restrict__ offs,
    const int* __restrict__ csr_col, const float* __restrict__ ss,
    unsigned short* __restrict__ agg, const int* __restrict__ flagp,
    int mode) {
  int b = blockIdx.x;
  int xcd = b & 7;
  int slice = xcd >> 1;
  int grp = (b >> 3) * 2 + (xcd & 1);   // 0..12499
  int node = grp * 4 + (threadIdx.x >> 6);
  if (node >= N_NODES) return;
  int lane = threadIdx.x & 63;
  int e4 = lane >> 4, c2 = lane & 15;
  int ch = slice * 32 + c2 * 2;
  int start = offs[node], end = offs[node + 1];
  float a0 = 0.f, a1 = 0.f;

  if (mode == 1) {
    const unsigned short* h = (const unsigned short*)src;
    float sc0 = ss[ch], sc1 = ss[ch + 1];
    float sh0 = ss[DIM + ch], sh1 = ss[DIM + ch + 1];
    int j = start + e4;
    for (; j + 12 < end; j += 16) {
      unsigned u0 = *(const unsigned*)(h + (size_t)csr_col[j] * DIM + ch);
      unsigned u1 = *(const unsigned*)(h + (size_t)csr_col[j + 4] * DIM + ch);
      unsigned u2 = *(const unsigned*)(h + (size_t)csr_col[j + 8] * DIM + ch);
      unsigned u3 = *(const unsigned*)(h + (size_t)csr_col[j + 12] * DIM + ch);
      a0 += fmaxf(bf2f((unsigned short)u0) * sc0 + sh0, 0.f) +
            fmaxf(bf2f((unsigned short)u1) * sc0 + sh0, 0.f) +
            fmaxf(bf2f((unsigned short)u2) * sc0 + sh0, 0.f) +
            fmaxf(bf2f((unsigned short)u3) * sc0 + sh0, 0.f);
      a1 += fmaxf(bf2f((unsigned short)(u0 >> 16)) * sc1 + sh1, 0.f) +
            fmaxf(bf2f((unsigned short)(u1 >> 16)) * sc1 + sh1, 0.f) +
            fmaxf(bf2f((unsigned short)(u2 >> 16)) * sc1 + sh1, 0.f) +
            fmaxf(bf2f((unsigned short)(u3 >> 16)) * sc1 + sh1, 0.f);
    }
    for (; j < end; j += 4) {
      unsigned u = *(const unsigned*)(h + (size_t)csr_col[j] * DIM + ch);
      a0 += fmaxf(bf2f((unsigned short)u) * sc0 + sh0, 0.f);
      a1 += fmaxf(bf2f((unsigned short)(u >> 16)) * sc1 + sh1, 0.f);
    }
  } else if (*flagp) {
    const unsigned short* x = (const unsigned short*)src;
    int j = start + e4;
    for (; j + 12 < end; j += 16) {
      unsigned u0 = *(const unsigned*)(x + (size_t)csr_col[j] * DIM + ch);
      unsigned u1 = *(const unsigned*)(x + (size_t)csr_col[j + 4] * DIM + ch);
      unsigned u2 = *(const unsigned*)(x + (size_t)csr_col[j + 8] * DIM + ch);
      unsigned u3 = *(const unsigned*)(x + (size_t)csr_col[j + 12] * DIM + ch);
      a0 += bf2f((unsigned short)u0) + bf2f((unsigned short)u1) +
            bf2f((unsigned short)u2) + bf2f((unsigned short)u3);
      a1 += bf2f((unsigned short)(u0 >> 16)) + bf2f((unsigned short)(u1 >> 16)) +
            bf2f((unsigned short)(u2 >> 16)) + bf2f((unsigned short)(u3 >> 16));
    }
    for (; j < end; j += 4) {
      unsigned u = *(const unsigned*)(x + (size_t)csr_col[j] * DIM + ch);
      a0 += bf2f((unsigned short)u);
      a1 += bf2f((unsigned short)(u >> 16));
    }
  } else {
    const float* x = (const float*)src;
    int j = start + e4;
    for (; j + 12 < end; j += 16) {
      float2 v0 = *(const float2*)(x + (size_t)csr_col[j] * DIM + ch);
      float2 v1 = *(const float2*)(x + (size_t)csr_col[j + 4] * DIM + ch);
      float2 v2 = *(const float2*)(x + (size_t)csr_col[j + 8] * DIM + ch);
      float2 v3 = *(const float2*)(x + (size_t)csr_col[j + 12] * DIM + ch);
      a0 += v0.x + v1.x + v2.x + v3.x;
      a1 += v0.y + v1.y + v2.y + v3.y;
    }
    for (; j < end; j += 4) {
      float2 v = *(const float2*)(x + (size_t)csr_col[j] * DIM + ch);
      a0 += v.x;
      a1 += v.y;
    }
  }
  a0 += __shfl_down(a0, 32); a1 += __shfl_down(a1, 32);
  a0 += __shfl_down(a0, 16); a1 += __shfl_down(a1, 16);
  if (e4 == 0) {
    unsigned o = (unsigned)f2bf(a0) | ((unsigned)f2bf(a1) << 16);
    *(unsigned*)(agg + (size_t)node * DIM + ch) = o;
  }
}

// ---- BN finalize: one block per channel ----
__global__ __launch_bounds__(256) void bn_fin_kernel(
    const float* __restrict__ ps, const float* __restrict__ g,
    const float* __restrict__ be, float* __restrict__ ss) {
  __shared__ float s2[256], q2[256];
  int c = blockIdx.x;
  int t = threadIdx.x;
  float s = 0.f, q = 0.f;
  for (int b = t; b < GEMM_GRID; b += 256) {
    s += ps[b * 256 + c];
    q += ps[b * 256 + 128 + c];
  }
  s2[t] = s; q2[t] = q;
  __syncthreads();
  for (int d = 128; d > 0; d >>= 1) {
    if (t < d) { s2[t] += s2[t + d]; q2[t] += q2[t + d]; }
    __syncthreads();
  }
  if (t == 0) {
    const float invN = 1.0f / (float)N_NODES;
    float m = s2[0] * invN;
    float v = q2[0] * invN - m * m;
    float scale = g[c] * rsqrtf(v + BN_EPS);
    ss[c] = scale;
    ss[DIM + c] = be[c] - m * scale;
  }
}

// ================= MFMA GEMM =================
__global__ __launch_bounds__(256) void gemm_kernel(
    const void* __restrict__ Ap, const unsigned short* __restrict__ agg,
    const unsigned short* __restrict__ PWm, const float* __restrict__ bias,
    const float* __restrict__ ss, void* __restrict__ Cp,
    float* __restrict__ ps, const int* __restrict__ flagp,
    int a_ext, int add_agg, int transform, int out_ext, int do_stats) {
  __shared__ unsigned short As[64 * 136];
  __shared__ float red_s[256];
  __shared__ float red_q[256];
  const int tid = threadIdx.x;
  const int row0 = blockIdx.x * 64;
  const int bf = *flagp;

  for (int i = 0; i < 8; ++i) {
    int G = tid + i * 256;
    int lrow = G >> 5;
    int ch = (G & 31) * 4;
    int grow = row0 + lrow;
    float4 v = make_float4(0.f, 0.f, 0.f, 0.f);
    if (grow < N_NODES) {
      if (a_ext && !bf) {
        v = *(const float4*)((const float*)Ap + (size_t)grow * DIM + ch);
      } else {
        ushort4 u = *(const ushort4*)((const unsigned short*)Ap +
                                      (size_t)grow * DIM + ch);
        v = make_float4(bf2f(u.x), bf2f(u.y), bf2f(u.z), bf2f(u.w));
      }
      if (transform) {
        float4 sc = *(const float4*)(ss + ch);
        float4 sh = *(const float4*)(ss + DIM + ch);
        v.x = fmaxf(v.x * sc.x + sh.x, 0.f);
        v.y = fmaxf(v.y * sc.y + sh.y, 0.f);
        v.z = fmaxf(v.z * sc.z + sh.z, 0.f);
        v.w = fmaxf(v.w * sc.w + sh.w, 0.f);
      }
      if (add_agg) {
        ushort4 au = *(const ushort4*)(agg + (size_t)grow * DIM + ch);
        v.x += bf2f(au.x); v.y += bf2f(au.y);
        v.z += bf2f(au.z); v.w += bf2f(au.w);
      }
    }
    ushort4 o;
    o.x = f2bf(v.x); o.y = f2bf(v.y); o.z = f2bf(v.z); o.w = f2bf(v.w);
    *(ushort4*)&As[lrow * 136 + ch] = o;
  }
  __syncthreads();

  const int wv = tid >> 6, lane = tid & 63;
  const int quad = lane >> 4, lo = lane & 15;
  accf4 acc[8];
#pragma unroll
  for (int nt = 0; nt < 8; ++nt) {
    acc[nt][0] = 0.f; acc[nt][1] = 0.f; acc[nt][2] = 0.f; acc[nt][3] = 0.f;
  }
#pragma unroll
  for (int kt = 0; kt < 4; ++kt) {
    bfrag8 a = *(const bfrag8*)&As[(wv * 16 + lo) * 136 + kt * 32 + quad * 8];
    const unsigned short* pw = PWm + kt * 4096 + lane * 8;
#pragma unroll
    for (int nt = 0; nt < 8; ++nt) {
      bfrag8 b = *(const bfrag8*)(pw + nt * 512);
      acc[nt] = __builtin_amdgcn_mfma_f32_16x16x32_bf16(a, b, acc[nt], 0, 0, 0);
    }
  }
  __syncthreads();

  if (out_ext && !bf) {
    float* Co = (float*)Cp;
#pragma unroll
    for (int nt = 0; nt < 8; ++nt) {
      float b = bias[nt * 16 + lo];
#pragma unroll
      for (int reg = 0; reg < 4; ++reg) {
        int grow = row0 + wv * 16 + quad * 4 + reg;
        if (grow < N_NODES)
          Co[(size_t)grow * DIM + nt * 16 + lo] = acc[nt][reg] + b;
      }
    }
  } else {
#pragma unroll
    for (int nt = 0; nt < 8; ++nt) {
      float b = bias[nt * 16 + lo];
#pragma unroll
      for (int reg = 0; reg < 4; ++reg) {
        As[(wv * 16 + quad * 4 + reg) * 136 + nt * 16 + lo] =
            f2bf(acc[nt][reg] + b);
      }
    }
    __syncthreads();
    unsigned short* Co = (unsigned short*)Cp;
    for (int i = 0; i < 8; ++i) {
      int G = tid + i * 256;
      int lrow = G >> 5, ch = (G & 31) * 4;
      int grow = row0 + lrow;
      if (grow < N_NODES)
        *(ushort4*)(Co + (size_t)grow * DIM + ch) =
            *(const ushort4*)&As[lrow * 136 + ch];
    }
    if (do_stats) {
      int c = tid & 127, rh = tid >> 7;
      int rmax = N_NODES - row0;
      if (rmax > 64) rmax = 64;
      int rend = rh * 32 + 32;
      if (rend > rmax) rend = rmax;
      float s = 0.f, q = 0.f;
      for (int r = rh * 32; r < rend; ++r) {
        float v = bf2f(As[r * 136 + c]);
        s += v; q += v * v;
      }
      red_s[tid] = s; red_q[tid] = q;
      __syncthreads();
      if (tid < 128) {
        ps[blockIdx.x * 256 + tid] = red_s[tid] + red_s[tid + 128];
        ps[blockIdx.x * 256 + 128 + tid] = red_q[tid] + red_q[tid + 128];
      }
    }
  }
}

extern "C" void kernel_launch(void* const* d_in, const int* in_sizes, int n_in,
                              void* d_out, int out_size, void* d_ws, size_t ws_size,
                              hipStream_t stream) {
  const void* x  = d_in[0];
  const int* row = (const int*)d_in[1];
  const int* col = (const int*)d_in[2];

  const size_t ND = (size_t)N_NODES * DIM;
  unsigned short* agg = (unsigned short*)d_ws;        // ND bf16
  unsigned short* hA  = agg + ND;                     // ND bf16
  unsigned short* hB  = hA + ND;                      // ND bf16
  unsigned short* PW  = hB + ND;                      // 4*16384 bf16
  float* PV    = (float*)(PW + 4 * 16384);            // 10*128 fp32
  float* ps    = PV + 10 * DIM;                       // GEMM_GRID*256 fp32
  float* ss    = ps + GEMM_GRID * 256;                // 3*256 fp32
  int*   flag  = (int*)(ss + 3 * 256);                // 1 (+pad)
  int*   deg   = flag + 4;                            // N
  int*   bcnt  = deg + N_NODES;                       // NBUCK
  int*   offs  = bcnt + NBUCK;                        // N+1
  int*   bsum  = offs + N_NODES + 1;                  // 256
  int*   bscan = bsum + 256;                          // 256
  int*   csr_col = bscan + 256;                       // E
  uint2* ebuf  = (uint2*)((((size_t)(csr_col + N_EDGES)) + 15) & ~(size_t)15);

  float* c0_b1f = PV + 0 * DIM; float* c0_gf  = PV + 1 * DIM;
  float* c0_bef = PV + 2 * DIM; float* c0_b2f = PV + 3 * DIM;
  float* bn0_gf = PV + 4 * DIM; float* bn0_bef= PV + 5 * DIM;
  float* c1_b1f = PV + 6 * DIM; float* c1_gf  = PV + 7 * DIM;
  float* c1_bef = PV + 8 * DIM; float* c1_b2f = PV + 9 * DIM;

  const int gath_grid  = 50000;              // sliced: 12500 groups x 4 slices
  const int grow_grid  = (N_NODES + 3) / 4;  // full-row: 12500

  detect_kernel<<<1, 64, 0, stream>>>((const unsigned short*)x, flag);

  PPtrs pp;
  pp.w[0] = d_in[3];  pp.w[1] = d_in[7];  pp.w[2] = d_in[11]; pp.w[3] = d_in[15];
  pp.v[0] = d_in[4];  pp.v[1] = d_in[5];  pp.v[2] = d_in[6];  pp.v[3] = d_in[8];
  pp.v[4] = d_in[9];  pp.v[5] = d_in[10]; pp.v[6] = d_in[12]; pp.v[7] = d_in[13];
  pp.v[8] = d_in[14]; pp.v[9] = d_in[16];
  prep_kernel<<<5, 256, 0, stream>>>(pp, PW, PV, flag);

  hipMemsetAsync(deg, 0, (N_NODES + NBUCK) * sizeof(int), stream);

  // ---- CSR build ----
  binA_kernel<<<BINA_BLOCKS, 256, 0, stream>>>(row, col, deg, bcnt, ebuf);
  bsum_kernel<<<NB, 256, 0, stream>>>(deg, bsum);
  bscan_kernel<<<1, 256, 0, stream>>>(bsum, bscan);
  offs_kernel<<<NB, 256, 0, stream>>>(deg, bscan, offs);
  binB_kernel<<<NBUCK, 256, 0, stream>>>(offs, bcnt, ebuf, csr_col);

  // ---- conv0 (A/B: full-row gather) ----
  gather_row_kernel<<<grow_grid, 256, 0, stream>>>(x, offs, csr_col, nullptr,
                                                   agg, flag, 0);
  gemm_kernel<<<GEMM_GRID, 256, 0, stream>>>(
      x, agg, PW + 0 * 16384, c0_b1f, nullptr, hA, ps, flag,
      1, 1, 0, 0, 1);
  bn_fin_kernel<<<128, 256, 0, stream>>>(ps, c0_gf, c0_bef, ss + 0);
  gemm_kernel<<<GEMM_GRID, 256, 0, stream>>>(
      hA, nullptr, PW + 1 * 16384, c0_b2f, ss + 0, hB, ps, flag,
      0, 0, 1, 0, 1);
  bn_fin_kernel<<<128, 256, 0, stream>>>(ps, bn0_gf, bn0_bef, ss + 256);

  // ---- conv1 (A/B: round-8 sliced gather) ----
  gather_kernel<<<gath_grid, 256, 0, stream>>>(hB, offs, csr_col, ss + 256,
                                               agg, flag, 1);
  gemm_kernel<<<GEMM_GRID, 256, 0, stream>>>(
      hB, agg, PW + 2 * 16384, c1_b1f, ss + 256, hA, ps, flag,
      0, 1, 1, 0, 1);
  bn_fin_kernel<<<128, 256, 0, stream>>>(ps, c1_gf, c1_bef, ss + 512);
  gemm_kernel<<<GEMM_GRID, 256, 0, stream>>>(
      hA, nullptr, PW + 3 * 16384, c1_b2f, ss + 512, d_out, nullptr, flag,
      0, 0, 1, 1, 0);
}

// Round 11
// 349.910 us; speedup vs baseline: 1.6633x; 1.1183x over previous
//
#include <hip/hip_runtime.h>

// GIN 2-layer forward, MI355X (gfx950). Round 11:
//  - full-row gather (1 coalesced 256B wave-load per edge) adopted for BOTH
//    layers (A/B winner of round 10: ~64us vs 80us sliced, same FETCH).
//  - gather MLP deepened: unroll-16 leading loop = one latency exposure per
//    mean-degree node (16 uniform index s_loads + 16 feature wave-loads).
//  - rest identical to round 10.

#define N_NODES 50000
#define N_EDGES 800000
#define DIM 128
#define BN_EPS 1e-5f
#define NB 196                  // ceil(N_NODES/256) scan blocks
#define GEMM_GRID 782           // ceil(N_NODES/64)
#define NBUCK 256
#define NPB 196                 // nodes per bucket
#define BCAP 4096               // max edges per bucket
#define BINA_BLOCKS 128
#define EPB (N_EDGES / BINA_BLOCKS)

using bfrag8 = __attribute__((ext_vector_type(8))) short;
using accf4  = __attribute__((ext_vector_type(4))) float;

__device__ __forceinline__ float bf2f(unsigned short u) {
  union { unsigned u32; float f; } c;
  c.u32 = ((unsigned)u) << 16;
  return c.f;
}
__device__ __forceinline__ unsigned short f2bf(float f) {
  union { float f; unsigned u32; } c;
  c.f = f;
  unsigned u = c.u32;
  return (unsigned short)((u + 0x7fffu + ((u >> 16) & 1u)) >> 16);  // RNE
}

// ---- dtype detector ----
__global__ void detect_kernel(const unsigned short* __restrict__ xs,
                              int* __restrict__ flag) {
  __shared__ int oks[64];
  int t = threadIdx.x;
  unsigned short u = xs[t * 2];
  int e = (u >> 7) & 0xFF;
  oks[t] = ((e >= 96 && e <= 134) || ((u & 0x7FFFu) == 0)) ? 1 : 0;
  __syncthreads();
  if (t == 0) {
    int c = 0;
    for (int i = 0; i < 64; ++i) c += oks[i];
    *flag = (c >= 56) ? 1 : 0;  // 1 = bf16, 0 = fp32
  }
}

// ---- prep: pack weights into MFMA B-frag layout + convert vectors ----
struct PPtrs { const void* w[4]; const void* v[10]; };

__global__ __launch_bounds__(256) void prep_kernel(
    PPtrs pp, unsigned short* __restrict__ PW, float* __restrict__ PV,
    const int* __restrict__ flagp) {
  int bf = *flagp;
  if (blockIdx.x < 4) {
    int mat = blockIdx.x;
    const void* src = pp.w[mat];
    unsigned short* dst = PW + (size_t)mat * 16384;
    for (int f = threadIdx.x; f < 2048; f += 256) {
      int kt = f >> 9, nt = (f >> 6) & 7, lane = f & 63;
      int kbase = kt * 32 + (lane >> 4) * 8;
      int n = nt * 16 + (lane & 15);
      unsigned short tmp[8];
      for (int j = 0; j < 8; ++j) {
        int idx = (kbase + j) * DIM + n;
        if (bf) tmp[j] = ((const unsigned short*)src)[idx];
        else    tmp[j] = f2bf(((const float*)src)[idx]);
      }
      for (int j = 0; j < 8; ++j) dst[f * 8 + j] = tmp[j];
    }
  } else {
    for (int j = threadIdx.x; j < 10 * DIM; j += 256) {
      int vec = j >> 7, idx = j & 127;
      float v;
      if (bf) v = bf2f(((const unsigned short*)pp.v[vec])[idx]);
      else    v = ((const float*)pp.v[vec])[idx];
      PV[j] = v;
    }
  }
}

// ================= CSR build =================
__global__ __launch_bounds__(256) void binA_kernel(
    const int* __restrict__ row, const int* __restrict__ col,
    int* __restrict__ deg, int* __restrict__ bcnt, uint2* __restrict__ ebuf) {
  __shared__ int hist[NBUCK];
  __shared__ int base[NBUCK];
  int t = threadIdx.x;
  int e0 = blockIdx.x * EPB;
  hist[t] = 0;
  __syncthreads();
  for (int i = t; i < EPB; i += 256) {
    int r = row[e0 + i];
    atomicAdd(&deg[r], 1);
    atomicAdd(&hist[r / NPB], 1);
  }
  __syncthreads();
  base[t] = atomicAdd(&bcnt[t], hist[t]);
  hist[t] = 0;
  __syncthreads();
  for (int i = t; i < EPB; i += 256) {
    int r = row[e0 + i];
    int c = col[e0 + i];
    int b = r / NPB;
    int rank = atomicAdd(&hist[b], 1);
    ebuf[(size_t)b * BCAP + base[b] + rank] = make_uint2((unsigned)r, (unsigned)c);
  }
}

__global__ __launch_bounds__(256) void bsum_kernel(
    const int* __restrict__ deg, int* __restrict__ bsum) {
  __shared__ int s[256];
  int i = blockIdx.x * 256 + threadIdx.x;
  s[threadIdx.x] = (i < N_NODES) ? deg[i] : 0;
  __syncthreads();
  for (int d = 128; d > 0; d >>= 1) {
    if (threadIdx.x < d) s[threadIdx.x] += s[threadIdx.x + d];
    __syncthreads();
  }
  if (threadIdx.x == 0) bsum[blockIdx.x] = s[0];
}

__global__ __launch_bounds__(256) void bscan_kernel(
    const int* __restrict__ bsum, int* __restrict__ bscan) {
  __shared__ int s[256];
  int t = threadIdx.x;
  int v = (t < NB) ? bsum[t] : 0;
  s[t] = v;
  __syncthreads();
  for (int d = 1; d < 256; d <<= 1) {
    int tv = (t >= d) ? s[t - d] : 0;
    __syncthreads();
    s[t] += tv;
    __syncthreads();
  }
  if (t < NB) bscan[t] = s[t] - v;  // exclusive
}

__global__ __launch_bounds__(256) void offs_kernel(
    const int* __restrict__ deg, const int* __restrict__ bscan,
    int* __restrict__ offs) {
  __shared__ int s[256];
  int t = threadIdx.x;
  int i = blockIdx.x * 256 + t;
  int v = (i < N_NODES) ? deg[i] : 0;
  s[t] = v;
  __syncthreads();
  for (int d = 1; d < 256; d <<= 1) {
    int tv = (t >= d) ? s[t - d] : 0;
    __syncthreads();
    s[t] += tv;
    __syncthreads();
  }
  if (i < N_NODES) {
    int excl = bscan[blockIdx.x] + s[t] - v;
    offs[i] = excl;
    if (i == N_NODES - 1) offs[N_NODES] = excl + v;
  }
}

__global__ __launch_bounds__(256) void binB_kernel(
    const int* __restrict__ offs, const int* __restrict__ bcnt,
    const uint2* __restrict__ ebuf, int* __restrict__ csr_col) {
  __shared__ int cur[NPB];
  __shared__ int seg[BCAP];
  int b = blockIdx.x;
  int nb = b * NPB;
  int nend = nb + NPB;
  if (nend > N_NODES) nend = N_NODES;
  int nn = nend - nb;
  int segbase = offs[nb];
  int seglen = offs[nend] - segbase;
  for (int i = threadIdx.x; i < nn; i += 256) cur[i] = offs[nb + i] - segbase;
  __syncthreads();
  int cnt = bcnt[b];
  const uint2* eb = ebuf + (size_t)b * BCAP;
  for (int i = threadIdx.x; i < cnt; i += 256) {
    uint2 e = eb[i];
    int slot = atomicAdd(&cur[e.x - (unsigned)nb], 1);
    seg[slot] = (int)e.y;
  }
  __syncthreads();
  for (int i = threadIdx.x; i < seglen; i += 256)
    csr_col[segbase + i] = seg[i];
}

// ================= full-row gather, unroll-16 =================
// Wave = 1 node; lane owns 2 channels (4B) => one wave instruction reads the
// whole 256B feature row of one neighbor. Unroll-16 = a full mean-degree
// node in one latency exposure. Index loads are wave-uniform -> scalar.
// mode 0: plain sum (src dtype per flag); mode 1: relu(v*sc+sh), bf16 src.
__global__ __launch_bounds__(256) void gather_row_kernel(
    const void* __restrict__ src, const int* __restrict__ offs,
    const int* __restrict__ csr_col, const float* __restrict__ ss,
    unsigned short* __restrict__ agg, const int* __restrict__ flagp,
    int mode) {
  int node = blockIdx.x * 4 + (threadIdx.x >> 6);
  if (node >= N_NODES) return;
  int lane = threadIdx.x & 63;
  int ch = lane * 2;
  int start = offs[node], end = offs[node + 1];
  float a0 = 0.f, a1 = 0.f;
  int bf = *flagp;
  float sc0 = 0.f, sc1 = 0.f, sh0 = 0.f, sh1 = 0.f;
  if (mode == 1) {
    sc0 = ss[ch]; sc1 = ss[ch + 1];
    sh0 = ss[DIM + ch]; sh1 = ss[DIM + ch + 1];
  }

  if (mode == 1 || bf) {
    const unsigned short* h = (const unsigned short*)src;
    int j = start;
    for (; j + 15 < end; j += 16) {
      int ix[16];
#pragma unroll
      for (int k = 0; k < 16; ++k) ix[k] = csr_col[j + k];
      unsigned u[16];
#pragma unroll
      for (int k = 0; k < 16; ++k)
        u[k] = *(const unsigned*)(h + (size_t)ix[k] * DIM + ch);
      if (mode == 1) {
#pragma unroll
        for (int k = 0; k < 16; ++k) {
          a0 += fmaxf(bf2f((unsigned short)u[k]) * sc0 + sh0, 0.f);
          a1 += fmaxf(bf2f((unsigned short)(u[k] >> 16)) * sc1 + sh1, 0.f);
        }
      } else {
#pragma unroll
        for (int k = 0; k < 16; ++k) {
          a0 += bf2f((unsigned short)u[k]);
          a1 += bf2f((unsigned short)(u[k] >> 16));
        }
      }
    }
    if (j + 7 < end) {
      int ix[8];
#pragma unroll
      for (int k = 0; k < 8; ++k) ix[k] = csr_col[j + k];
      unsigned u[8];
#pragma unroll
      for (int k = 0; k < 8; ++k)
        u[k] = *(const unsigned*)(h + (size_t)ix[k] * DIM + ch);
#pragma unroll
      for (int k = 0; k < 8; ++k) {
        if (mode == 1) {
          a0 += fmaxf(bf2f((unsigned short)u[k]) * sc0 + sh0, 0.f);
          a1 += fmaxf(bf2f((unsigned short)(u[k] >> 16)) * sc1 + sh1, 0.f);
        } else {
          a0 += bf2f((unsigned short)u[k]);
          a1 += bf2f((unsigned short)(u[k] >> 16));
        }
      }
      j += 8;
    }
    if (j + 3 < end) {
      int ix[4];
#pragma unroll
      for (int k = 0; k < 4; ++k) ix[k] = csr_col[j + k];
      unsigned u[4];
#pragma unroll
      for (int k = 0; k < 4; ++k)
        u[k] = *(const unsigned*)(h + (size_t)ix[k] * DIM + ch);
#pragma unroll
      for (int k = 0; k < 4; ++k) {
        if (mode == 1) {
          a0 += fmaxf(bf2f((unsigned short)u[k]) * sc0 + sh0, 0.f);
          a1 += fmaxf(bf2f((unsigned short)(u[k] >> 16)) * sc1 + sh1, 0.f);
        } else {
          a0 += bf2f((unsigned short)u[k]);
          a1 += bf2f((unsigned short)(u[k] >> 16));
        }
      }
      j += 4;
    }
    for (; j < end; ++j) {
      unsigned u = *(const unsigned*)(h + (size_t)csr_col[j] * DIM + ch);
      if (mode == 1) {
        a0 += fmaxf(bf2f((unsigned short)u) * sc0 + sh0, 0.f);
        a1 += fmaxf(bf2f((unsigned short)(u >> 16)) * sc1 + sh1, 0.f);
      } else {
        a0 += bf2f((unsigned short)u);
        a1 += bf2f((unsigned short)(u >> 16));
      }
    }
  } else {
    const float* x = (const float*)src;
    int j = start;
    for (; j + 7 < end; j += 8) {
      int ix[8];
#pragma unroll
      for (int k = 0; k < 8; ++k) ix[k] = csr_col[j + k];
#pragma unroll
      for (int k = 0; k < 8; ++k) {
        float2 v = *(const float2*)(x + (size_t)ix[k] * DIM + ch);
        a0 += v.x; a1 += v.y;
      }
    }
    for (; j < end; ++j) {
      float2 v = *(const float2*)(x + (size_t)csr_col[j] * DIM + ch);
      a0 += v.x; a1 += v.y;
    }
  }
  unsigned o = (unsigned)f2bf(a0) | ((unsigned)f2bf(a1) << 16);
  *(unsigned*)(agg + (size_t)node * DIM + ch) = o;
}

// ---- BN finalize: one block per channel ----
__global__ __launch_bounds__(256) void bn_fin_kernel(
    const float* __restrict__ ps, const float* __restrict__ g,
    const float* __restrict__ be, float* __restrict__ ss) {
  __shared__ float s2[256], q2[256];
  int c = blockIdx.x;
  int t = threadIdx.x;
  float s = 0.f, q = 0.f;
  for (int b = t; b < GEMM_GRID; b += 256) {
    s += ps[b * 256 + c];
    q += ps[b * 256 + 128 + c];
  }
  s2[t] = s; q2[t] = q;
  __syncthreads();
  for (int d = 128; d > 0; d >>= 1) {
    if (t < d) { s2[t] += s2[t + d]; q2[t] += q2[t + d]; }
    __syncthreads();
  }
  if (t == 0) {
    const float invN = 1.0f / (float)N_NODES;
    float m = s2[0] * invN;
    float v = q2[0] * invN - m * m;
    float scale = g[c] * rsqrtf(v + BN_EPS);
    ss[c] = scale;
    ss[DIM + c] = be[c] - m * scale;
  }
}

// ================= MFMA GEMM =================
__global__ __launch_bounds__(256) void gemm_kernel(
    const void* __restrict__ Ap, const unsigned short* __restrict__ agg,
    const unsigned short* __restrict__ PWm, const float* __restrict__ bias,
    const float* __restrict__ ss, void* __restrict__ Cp,
    float* __restrict__ ps, const int* __restrict__ flagp,
    int a_ext, int add_agg, int transform, int out_ext, int do_stats) {
  __shared__ unsigned short As[64 * 136];
  __shared__ float red_s[256];
  __shared__ float red_q[256];
  const int tid = threadIdx.x;
  const int row0 = blockIdx.x * 64;
  const int bf = *flagp;

  for (int i = 0; i < 8; ++i) {
    int G = tid + i * 256;
    int lrow = G >> 5;
    int ch = (G & 31) * 4;
    int grow = row0 + lrow;
    float4 v = make_float4(0.f, 0.f, 0.f, 0.f);
    if (grow < N_NODES) {
      if (a_ext && !bf) {
        v = *(const float4*)((const float*)Ap + (size_t)grow * DIM + ch);
      } else {
        ushort4 u = *(const ushort4*)((const unsigned short*)Ap +
                                      (size_t)grow * DIM + ch);
        v = make_float4(bf2f(u.x), bf2f(u.y), bf2f(u.z), bf2f(u.w));
      }
      if (transform) {
        float4 sc = *(const float4*)(ss + ch);
        float4 sh = *(const float4*)(ss + DIM + ch);
        v.x = fmaxf(v.x * sc.x + sh.x, 0.f);
        v.y = fmaxf(v.y * sc.y + sh.y, 0.f);
        v.z = fmaxf(v.z * sc.z + sh.z, 0.f);
        v.w = fmaxf(v.w * sc.w + sh.w, 0.f);
      }
      if (add_agg) {
        ushort4 au = *(const ushort4*)(agg + (size_t)grow * DIM + ch);
        v.x += bf2f(au.x); v.y += bf2f(au.y);
        v.z += bf2f(au.z); v.w += bf2f(au.w);
      }
    }
    ushort4 o;
    o.x = f2bf(v.x); o.y = f2bf(v.y); o.z = f2bf(v.z); o.w = f2bf(v.w);
    *(ushort4*)&As[lrow * 136 + ch] = o;
  }
  __syncthreads();

  const int wv = tid >> 6, lane = tid & 63;
  const int quad = lane >> 4, lo = lane & 15;
  accf4 acc[8];
#pragma unroll
  for (int nt = 0; nt < 8; ++nt) {
    acc[nt][0] = 0.f; acc[nt][1] = 0.f; acc[nt][2] = 0.f; acc[nt][3] = 0.f;
  }
#pragma unroll
  for (int kt = 0; kt < 4; ++kt) {
    bfrag8 a = *(const bfrag8*)&As[(wv * 16 + lo) * 136 + kt * 32 + quad * 8];
    const unsigned short* pw = PWm + kt * 4096 + lane * 8;
#pragma unroll
    for (int nt = 0; nt < 8; ++nt) {
      bfrag8 b = *(const bfrag8*)(pw + nt * 512);
      acc[nt] = __builtin_amdgcn_mfma_f32_16x16x32_bf16(a, b, acc[nt], 0, 0, 0);
    }
  }
  __syncthreads();

  if (out_ext && !bf) {
    float* Co = (float*)Cp;
#pragma unroll
    for (int nt = 0; nt < 8; ++nt) {
      float b = bias[nt * 16 + lo];
#pragma unroll
      for (int reg = 0; reg < 4; ++reg) {
        int grow = row0 + wv * 16 + quad * 4 + reg;
        if (grow < N_NODES)
          Co[(size_t)grow * DIM + nt * 16 + lo] = acc[nt][reg] + b;
      }
    }
  } else {
#pragma unroll
    for (int nt = 0; nt < 8; ++nt) {
      float b = bias[nt * 16 + lo];
#pragma unroll
      for (int reg = 0; reg < 4; ++reg) {
        As[(wv * 16 + quad * 4 + reg) * 136 + nt * 16 + lo] =
            f2bf(acc[nt][reg] + b);
      }
    }
    __syncthreads();
    unsigned short* Co = (unsigned short*)Cp;
    for (int i = 0; i < 8; ++i) {
      int G = tid + i * 256;
      int lrow = G >> 5, ch = (G & 31) * 4;
      int grow = row0 + lrow;
      if (grow < N_NODES)
        *(ushort4*)(Co + (size_t)grow * DIM + ch) =
            *(const ushort4*)&As[lrow * 136 + ch];
    }
    if (do_stats) {
      int c = tid & 127, rh = tid >> 7;
      int rmax = N_NODES - row0;
      if (rmax > 64) rmax = 64;
      int rend = rh * 32 + 32;
      if (rend > rmax) rend = rmax;
      float s = 0.f, q = 0.f;
      for (int r = rh * 32; r < rend; ++r) {
        float v = bf2f(As[r * 136 + c]);
        s += v; q += v * v;
      }
      red_s[tid] = s; red_q[tid] = q;
      __syncthreads();
      if (tid < 128) {
        ps[blockIdx.x * 256 + tid] = red_s[tid] + red_s[tid + 128];
        ps[blockIdx.x * 256 + 128 + tid] = red_q[tid] + red_q[tid + 128];
      }
    }
  }
}

extern "C" void kernel_launch(void* const* d_in, const int* in_sizes, int n_in,
                              void* d_out, int out_size, void* d_ws, size_t ws_size,
                              hipStream_t stream) {
  const void* x  = d_in[0];
  const int* row = (const int*)d_in[1];
  const int* col = (const int*)d_in[2];

  const size_t ND = (size_t)N_NODES * DIM;
  unsigned short* agg = (unsigned short*)d_ws;        // ND bf16
  unsigned short* hA  = agg + ND;                     // ND bf16
  unsigned short* hB  = hA + ND;                      // ND bf16
  unsigned short* PW  = hB + ND;                      // 4*16384 bf16
  float* PV    = (float*)(PW + 4 * 16384);            // 10*128 fp32
  float* ps    = PV + 10 * DIM;                       // GEMM_GRID*256 fp32
  float* ss    = ps + GEMM_GRID * 256;                // 3*256 fp32
  int*   flag  = (int*)(ss + 3 * 256);                // 1 (+pad)
  int*   deg   = flag + 4;                            // N
  int*   bcnt  = deg + N_NODES;                       // NBUCK
  int*   offs  = bcnt + NBUCK;                        // N+1
  int*   bsum  = offs + N_NODES + 1;                  // 256
  int*   bscan = bsum + 256;                          // 256
  int*   csr_col = bscan + 256;                       // E
  uint2* ebuf  = (uint2*)((((size_t)(csr_col + N_EDGES)) + 15) & ~(size_t)15);

  float* c0_b1f = PV + 0 * DIM; float* c0_gf  = PV + 1 * DIM;
  float* c0_bef = PV + 2 * DIM; float* c0_b2f = PV + 3 * DIM;
  float* bn0_gf = PV + 4 * DIM; float* bn0_bef= PV + 5 * DIM;
  float* c1_b1f = PV + 6 * DIM; float* c1_gf  = PV + 7 * DIM;
  float* c1_bef = PV + 8 * DIM; float* c1_b2f = PV + 9 * DIM;

  const int grow_grid = (N_NODES + 3) / 4;  // 12500

  detect_kernel<<<1, 64, 0, stream>>>((const unsigned short*)x, flag);

  PPtrs pp;
  pp.w[0] = d_in[3];  pp.w[1] = d_in[7];  pp.w[2] = d_in[11]; pp.w[3] = d_in[15];
  pp.v[0] = d_in[4];  pp.v[1] = d_in[5];  pp.v[2] = d_in[6];  pp.v[3] = d_in[8];
  pp.v[4] = d_in[9];  pp.v[5] = d_in[10]; pp.v[6] = d_in[12]; pp.v[7] = d_in[13];
  pp.v[8] = d_in[14]; pp.v[9] = d_in[16];
  prep_kernel<<<5, 256, 0, stream>>>(pp, PW, PV, flag);

  hipMemsetAsync(deg, 0, (N_NODES + NBUCK) * sizeof(int), stream);

  // ---- CSR build ----
  binA_kernel<<<BINA_BLOCKS, 256, 0, stream>>>(row, col, deg, bcnt, ebuf);
  bsum_kernel<<<NB, 256, 0, stream>>>(deg, bsum);
  bscan_kernel<<<1, 256, 0, stream>>>(bsum, bscan);
  offs_kernel<<<NB, 256, 0, stream>>>(deg, bscan, offs);
  binB_kernel<<<NBUCK, 256, 0, stream>>>(offs, bcnt, ebuf, csr_col);

  // ---- conv0 ----
  gather_row_kernel<<<grow_grid, 256, 0, stream>>>(x, offs, csr_col, nullptr,
                                                   agg, flag, 0);
  gemm_kernel<<<GEMM_GRID, 256, 0, stream>>>(
      x, agg, PW + 0 * 16384, c0_b1f, nullptr, hA, ps, flag,
      1, 1, 0, 0, 1);
  bn_fin_kernel<<<128, 256, 0, stream>>>(ps, c0_gf, c0_bef, ss + 0);
  gemm_kernel<<<GEMM_GRID, 256, 0, stream>>>(
      hA, nullptr, PW + 1 * 16384, c0_b2f, ss + 0, hB, ps, flag,
      0, 0, 1, 0, 1);
  bn_fin_kernel<<<128, 256, 0, stream>>>(ps, bn0_gf, bn0_bef, ss + 256);

  // ---- conv1 ----
  gather_row_kernel<<<grow_grid, 256, 0, stream>>>(hB, offs, csr_col, ss + 256,
                                                   agg, flag, 1);
  gemm_kernel<<<GEMM_GRID, 256, 0, stream>>>(
      hB, agg, PW + 2 * 16384, c1_b1f, ss + 256, hA, ps, flag,
      0, 1, 1, 0, 1);
  bn_fin_kernel<<<128, 256, 0, stream>>>(ps, c1_gf, c1_bef, ss + 512);
  gemm_kernel<<<GEMM_GRID, 256, 0, stream>>>(
      hA, nullptr, PW + 3 * 16384, c1_b2f, ss + 512, d_out, nullptr, flag,
      0, 0, 1, 1, 0);
}